// Round 1
// baseline (2270.093 us; speedup 1.0000x reference)
//
#include <hip/hip_runtime.h>

// MixProp: out[b,o,v,l] = bias[o] + sum_c W[o,c] * Hcat[b,c,v,l]
// Hcat = concat(X, H1, H2, H3) over channels; Hk = beta*X + (1-beta)*A'*H_{k-1}
// A' = row-normalized (A + I).
//
// Baseline round: pure fp32. Per-batch sequencing keeps ws at 51.4 MB.

#define NODES 512
#define SEQL  256
#define CIN   32
#define COUT  64
#define NB    8
#define PLANE (NODES * SEQL)     // 131072 elements per (b,c) plane
#define BETA_F 0.05f
#define OMB_F  0.95f

// ---------------------------------------------------------------------------
// A' = (A + I) / rowsum
__global__ __launch_bounds__(256) void norm_A_kernel(const float* __restrict__ A,
                                                     float* __restrict__ Ap) {
    const int v = blockIdx.x;
    const int t = threadIdx.x;
    __shared__ float red[256];
    float s = 0.f;
    for (int w = t; w < NODES; w += 256) {
        s += A[v * NODES + w] + (w == v ? 1.f : 0.f);
    }
    red[t] = s;
    __syncthreads();
    for (int off = 128; off > 0; off >>= 1) {
        if (t < off) red[t] += red[t + off];
        __syncthreads();
    }
    const float inv = 1.f / red[0];
    for (int w = t; w < NODES; w += 256) {
        const float a = A[v * NODES + w] + (w == v ? 1.f : 0.f);
        Ap[v * NODES + w] = a * inv;
    }
}

// ---------------------------------------------------------------------------
// Wt[c][o] = W[o][c]  (so final-conv weight reads are uniform AND contiguous
// in o -> compiler emits s_load_dwordx16 from the scalar pipe)
__global__ __launch_bounds__(256) void prep_W_kernel(const float* __restrict__ W,
                                                     float* __restrict__ Wt) {
    const int i = blockIdx.x * 256 + threadIdx.x;  // 0 .. 8191
    const int o = i >> 7;     // / 128
    const int c = i & 127;
    Wt[c * COUT + o] = W[i];
}

// ---------------------------------------------------------------------------
// One hop for one (b): for each channel c (blockIdx.z):
//   D[v,l] = beta*X[v,l] + (1-beta) * sum_w Ap[v,w]*S[w,l]
// 64x64 output tile per block, 4x4 microtile per thread, K-step 16.
__global__ __launch_bounds__(256) void prop_kernel(
    const float* __restrict__ Ap,
    const float* __restrict__ src,   // [CIN][NODES][SEQL] (one batch)
    const float* __restrict__ Xb,    // same layout
    float* __restrict__ dst)
{
    const int lt = blockIdx.x * 64;
    const int vt = blockIdx.y * 64;
    const int c  = blockIdx.z;
    const float* S  = src + (size_t)c * PLANE;
    const float* Xc = Xb  + (size_t)c * PLANE;
    float*       D  = dst + (size_t)c * PLANE;

    __shared__ float As[64][17];   // +1 pad breaks stride-16 bank aliasing
    __shared__ float Bs[16][64];

    const int t  = threadIdx.x;
    const int tx = t & 15;
    const int ty = t >> 4;

    // staging index maps (float4 per thread per tile)
    const int arow = t >> 2;          // 0..63
    const int acol = (t & 3) * 4;     // 0,4,8,12
    const int brow = t >> 4;          // 0..15
    const int bcol = (t & 15) * 4;    // 0..60

    float acc[4][4] = {{0.f}};

    for (int kk = 0; kk < NODES; kk += 16) {
        const float4 av = *(const float4*)(Ap + (size_t)(vt + arow) * NODES + kk + acol);
        As[arow][acol + 0] = av.x;
        As[arow][acol + 1] = av.y;
        As[arow][acol + 2] = av.z;
        As[arow][acol + 3] = av.w;
        const float4 bv = *(const float4*)(S + (size_t)(kk + brow) * SEQL + lt + bcol);
        *(float4*)(&Bs[brow][bcol]) = bv;
        __syncthreads();
#pragma unroll
        for (int k = 0; k < 16; ++k) {
            const float a0 = As[ty * 4 + 0][k];
            const float a1 = As[ty * 4 + 1][k];
            const float a2 = As[ty * 4 + 2][k];
            const float a3 = As[ty * 4 + 3][k];
            const float4 b4 = *(const float4*)(&Bs[k][tx * 4]);
            acc[0][0] += a0 * b4.x; acc[0][1] += a0 * b4.y; acc[0][2] += a0 * b4.z; acc[0][3] += a0 * b4.w;
            acc[1][0] += a1 * b4.x; acc[1][1] += a1 * b4.y; acc[1][2] += a1 * b4.z; acc[1][3] += a1 * b4.w;
            acc[2][0] += a2 * b4.x; acc[2][1] += a2 * b4.y; acc[2][2] += a2 * b4.z; acc[2][3] += a2 * b4.w;
            acc[3][0] += a3 * b4.x; acc[3][1] += a3 * b4.y; acc[3][2] += a3 * b4.z; acc[3][3] += a3 * b4.w;
        }
        __syncthreads();
    }

    // epilogue: mix with X, vectorized store
#pragma unroll
    for (int i = 0; i < 4; ++i) {
        const int v = vt + ty * 4 + i;
        const int l = lt + tx * 4;
        const float4 xv = *(const float4*)(Xc + (size_t)v * SEQL + l);
        float4 ov;
        ov.x = BETA_F * xv.x + OMB_F * acc[i][0];
        ov.y = BETA_F * xv.y + OMB_F * acc[i][1];
        ov.z = BETA_F * xv.z + OMB_F * acc[i][2];
        ov.w = BETA_F * xv.w + OMB_F * acc[i][3];
        *(float4*)(D + (size_t)v * SEQL + l) = ov;
    }
}

// ---------------------------------------------------------------------------
// Final 1x1 conv for one batch: out[o,v,l] = bias[o] + sum over 128 channels.
// Thread = one (v,l) column, 64 accumulators; weights via uniform scalar loads.
__global__ __launch_bounds__(256) void final_kernel(
    const float* __restrict__ Xb,
    const float* __restrict__ H1,
    const float* __restrict__ H2,
    const float* __restrict__ H3,
    const float* __restrict__ Wt,     // [128][64] transposed weights
    const float* __restrict__ bias,
    float* __restrict__ outb)
{
    const int v = blockIdx.x;
    const int l = threadIdx.x;
    const size_t off = (size_t)v * SEQL + l;

    float acc[COUT];
#pragma unroll
    for (int o = 0; o < COUT; ++o) acc[o] = bias[o];

    const float* planes[4] = {Xb, H1, H2, H3};
#pragma unroll
    for (int g = 0; g < 4; ++g) {
        const float* P = planes[g] + off;
        for (int c = 0; c < CIN; ++c) {
            const float x = P[(size_t)c * PLANE];
            const float* wrow = Wt + (size_t)(g * CIN + c) * COUT;  // uniform, contiguous
#pragma unroll
            for (int o = 0; o < COUT; ++o)
                acc[o] += wrow[o] * x;
        }
    }
#pragma unroll
    for (int o = 0; o < COUT; ++o)
        outb[(size_t)o * PLANE + off] = acc[o];
}

// ---------------------------------------------------------------------------
extern "C" void kernel_launch(void* const* d_in, const int* in_sizes, int n_in,
                              void* d_out, int out_size, void* d_ws, size_t ws_size,
                              hipStream_t stream) {
    (void)in_sizes; (void)n_in; (void)out_size; (void)ws_size;
    const float* X    = (const float*)d_in[0];
    const float* A    = (const float*)d_in[1];
    const float* W    = (const float*)d_in[2];
    const float* bias = (const float*)d_in[3];
    float* out = (float*)d_out;
    float* ws  = (float*)d_ws;

    // ws layout (floats): A' | H1 | H2 | H3 | Wt  = 51.4 MB total
    float* Ap = ws;                     // 512*512       = 262144
    float* H1 = Ap + 262144;            // 32*512*256    = 4194304 (one batch)
    float* H2 = H1 + 4194304;
    float* H3 = H2 + 4194304;
    float* Wt = H3 + 4194304;           // 8192

    norm_A_kernel<<<dim3(NODES), dim3(256), 0, stream>>>(A, Ap);
    prep_W_kernel<<<dim3(32), dim3(256), 0, stream>>>(W, Wt);

    const dim3 pgrid(SEQL / 64, NODES / 64, CIN);  // (4, 8, 32) = 1024 blocks

    for (int b = 0; b < NB; ++b) {
        const float* Xb   = X   + (size_t)b * CIN  * PLANE;
        float*       outb = out + (size_t)b * COUT * PLANE;
        prop_kernel<<<pgrid, 256, 0, stream>>>(Ap, Xb, Xb, H1);
        prop_kernel<<<pgrid, 256, 0, stream>>>(Ap, H1, Xb, H2);
        prop_kernel<<<pgrid, 256, 0, stream>>>(Ap, H2, Xb, H3);
        final_kernel<<<dim3(NODES), dim3(256), 0, stream>>>(Xb, H1, H2, H3, Wt, bias, outb);
    }
}

// Round 2
// 797.770 us; speedup vs baseline: 2.8455x; 2.8455x over previous
//
#include <hip/hip_runtime.h>

// MixProp on MI355X — MFMA round.
// Pipeline (all intermediates f16 in ws):
//   A''  = (1-beta) * rownorm(A+I)                        [v][w]   f16
//   Xt   = X^T per (b,c) plane                            [l][w]   f16
//   Ht_k = (A''·H_{k-1})^T + beta*Xt   (MFMA f16 GEMM)    [l][v]   f16
//   Hn_k = Ht_k^T (natural layout for final conv)         [v][l]   f16
//   out  = bias + W·[X,H1,H2,H3]  (v_dot2_f32_f16 conv)   fp32
//
// GEMM orientation D[m=l][n=v] = sum_w Ht[l,w]*A''[v,w]: both operands are
// K(w)-contiguous -> global_load_lds width=16 staging for A and B, with an
// XOR-of-row chunk swizzle applied in the per-lane GLOBAL address (LDS dest
// is forced contiguous) so fragment ds_read_b128s are bank-conflict-free.

#define NODES 512
#define SEQL  256
#define CIN   32
#define COUT  64
#define NB    8
#define PLANE (NODES * SEQL)   // 131072
#define BETA_F 0.05f

typedef _Float16 f16x8 __attribute__((ext_vector_type(8)));
typedef _Float16 f16x2 __attribute__((ext_vector_type(2)));
typedef float    f32x4 __attribute__((ext_vector_type(4)));

typedef const unsigned int __attribute__((address_space(1)))* gptr_t;
typedef unsigned int __attribute__((address_space(3)))* lptr_t;

__device__ __forceinline__ void gload16(const void* g, void* l) {
    __builtin_amdgcn_global_load_lds((gptr_t)g, (lptr_t)l, 16, 0, 0);
}

__device__ __forceinline__ unsigned short f2h(float f) {
    _Float16 h = (_Float16)f;
    return __builtin_bit_cast(unsigned short, h);
}

// ---------------------------------------------------------------------------
// A'' = (1-beta) * (A+I)/rowsum, cast to f16
__global__ __launch_bounds__(256) void norm_A_kernel(const float* __restrict__ A,
                                                     _Float16* __restrict__ Apb) {
    const int v = blockIdx.x;
    const int t = threadIdx.x;
    __shared__ float red[256];
    float s = 0.f;
    for (int w = t; w < NODES; w += 256)
        s += A[v * NODES + w] + (w == v ? 1.f : 0.f);
    red[t] = s;
    __syncthreads();
    for (int off = 128; off > 0; off >>= 1) {
        if (t < off) red[t] += red[t + off];
        __syncthreads();
    }
    const float inv = (1.f - BETA_F) / red[0];
    for (int w = t; w < NODES; w += 256) {
        const float a = A[v * NODES + w] + (w == v ? 1.f : 0.f);
        Apb[v * NODES + w] = (_Float16)(a * inv);
    }
}

// ---------------------------------------------------------------------------
// Wt[c][o] fp32 (for the fp32-X group) and Wp[pair][o] packed f16x2
__global__ __launch_bounds__(256) void prep_W_kernel(const float* __restrict__ W,
                                                     float* __restrict__ Wt,
                                                     unsigned int* __restrict__ Wp) {
    const int i = blockIdx.x * 256 + threadIdx.x;   // 0..8191
    const int o = i >> 7, c = i & 127;
    Wt[c * COUT + o] = W[i];
    if (i < 4096) {
        const int p = i >> 6, oo = i & 63;
        Wp[i] = (unsigned)f2h(W[oo * 128 + 2 * p]) |
                ((unsigned)f2h(W[oo * 128 + 2 * p + 1]) << 16);
    }
}

// ---------------------------------------------------------------------------
// Xt[(b,c)][l][v] f16 from X fp32 [(b,c)][v][l].  64x64 LDS tile transpose.
// grid: (l-tiles=4, v-tiles=8, chunk=256)
__global__ __launch_bounds__(256) void prep_X_kernel(const float* __restrict__ X,
                                                     unsigned short* __restrict__ Xt) {
    const int l0 = blockIdx.x * 64, v0 = blockIdx.y * 64;
    const size_t coff = (size_t)blockIdx.z * PLANE;
    __shared__ unsigned short t[64][66];   // [l][v], pad 66: conflict-light
    const int rr = threadIdx.x >> 4;
    const int cc = (threadIdx.x & 15) * 4;
#pragma unroll
    for (int rep = 0; rep < 4; ++rep) {
        const int vl = rep * 16 + rr;
        const float4 f = *(const float4*)(X + coff + (size_t)(v0 + vl) * SEQL + l0 + cc);
        t[cc + 0][vl] = f2h(f.x);
        t[cc + 1][vl] = f2h(f.y);
        t[cc + 2][vl] = f2h(f.z);
        t[cc + 3][vl] = f2h(f.w);
    }
    __syncthreads();
#pragma unroll
    for (int rep = 0; rep < 4; ++rep) {
        const int ll = rep * 16 + rr;
        ushort4 d;
        d.x = t[ll][cc + 0]; d.y = t[ll][cc + 1];
        d.z = t[ll][cc + 2]; d.w = t[ll][cc + 3];
        *(ushort4*)(Xt + coff + (size_t)(l0 + ll) * NODES + v0 + cc) = d;
    }
}

// ---------------------------------------------------------------------------
// Hn[(b,c)][v][l] = Ht[(b,c)][l][v]^T  (pure f16 move)
// grid: (v-tiles=8, l-tiles=4, chunk=256)
__global__ __launch_bounds__(256) void transpose_h_kernel(const unsigned short* __restrict__ src,
                                                          unsigned short* __restrict__ dst) {
    const int v0 = blockIdx.x * 64, l0 = blockIdx.y * 64;
    const size_t coff = (size_t)blockIdx.z * PLANE;
    __shared__ unsigned short t[64][66];   // [v][l]
    const int rr = threadIdx.x >> 4;
    const int cc = (threadIdx.x & 15) * 4;
#pragma unroll
    for (int rep = 0; rep < 4; ++rep) {
        const int ll = rep * 16 + rr;
        const ushort4 s = *(const ushort4*)(src + coff + (size_t)(l0 + ll) * NODES + v0 + cc);
        t[cc + 0][ll] = s.x; t[cc + 1][ll] = s.y;
        t[cc + 2][ll] = s.z; t[cc + 3][ll] = s.w;
    }
    __syncthreads();
#pragma unroll
    for (int rep = 0; rep < 4; ++rep) {
        const int vl = rep * 16 + rr;
        ushort4 d;
        d.x = t[vl][cc + 0]; d.y = t[vl][cc + 1];
        d.z = t[vl][cc + 2]; d.w = t[vl][cc + 3];
        *(ushort4*)(dst + coff + (size_t)(v0 + vl) * SEQL + l0 + cc) = d;
    }
}

// ---------------------------------------------------------------------------
// Ht_out[l][v] = sum_w Ht_in[l][w] * A''[v][w]  + beta * Xt[l][v]
// Block: 128(l) x 128(v) tile, 4 waves of 64x64, BK=64, mfma f32_16x16x32_f16.
// grid: (v-tiles=4, l-tiles=2, chunk=256)
__global__ __launch_bounds__(256) void prop_mfma_kernel(
    const _Float16* __restrict__ Apb,    // [512][512], (1-beta) folded
    const _Float16* __restrict__ Hin,    // [chunk][l=256][w=512]
    const _Float16* __restrict__ Xt,     // [chunk][l=256][v=512]
    _Float16* __restrict__ Hout)         // [chunk][l=256][v=512]
{
    __shared__ _Float16 Asl[128 * 64];   // rows m=l, BK=64 w
    __shared__ _Float16 Bsl[128 * 64];   // rows n=v, BK=64 w

    const int tid  = threadIdx.x;
    const int wave = tid >> 6;
    const int lane = tid & 63;
    const int n0 = blockIdx.x * 128;     // v
    const int m0 = blockIdx.y * 128;     // l
    const size_t coff = (size_t)blockIdx.z * PLANE;
    const _Float16* Asrc = Hin + coff;

    const int wm = (wave >> 1) * 64;
    const int wn = (wave & 1) * 64;
    const int lane15 = lane & 15;
    const int quad = lane >> 4;
    const int srow = lane >> 3;          // staging: row within 8-row group
    const int spos = lane & 7;           // staging: 16B chunk slot

    f32x4 acc[4][4] = {};

    for (int kk = 0; kk < 8; ++kk) {
        const int k0 = kk * 64;
        // --- stage A (Hin rows l) and B (A'' rows v), XOR-swizzled source ---
#pragma unroll
        for (int j = 0; j < 4; ++j) {
            const int r = wave * 32 + j * 8 + srow;            // tile-local row
            const int gc = k0 + ((spos ^ (r & 7)) << 3);       // swizzled global col
            gload16(Asrc + (size_t)(m0 + r) * NODES + gc, &Asl[(wave * 32 + j * 8) * 64]);
            gload16(Apb  + (size_t)(n0 + r) * NODES + gc, &Bsl[(wave * 32 + j * 8) * 64]);
        }
        __syncthreads();
        // --- compute ---
#pragma unroll
        for (int ks = 0; ks < 2; ++ks) {
            f16x8 af[4], bf[4];
#pragma unroll
            for (int mt = 0; mt < 4; ++mt) {
                const int m = wm + mt * 16 + lane15;
                const int pos = (ks * 4 + quad) ^ (m & 7);
                af[mt] = *(const f16x8*)&Asl[m * 64 + pos * 8];
            }
#pragma unroll
            for (int nt = 0; nt < 4; ++nt) {
                const int n = wn + nt * 16 + lane15;
                const int pos = (ks * 4 + quad) ^ (n & 7);
                bf[nt] = *(const f16x8*)&Bsl[n * 64 + pos * 8];
            }
#pragma unroll
            for (int mt = 0; mt < 4; ++mt)
#pragma unroll
                for (int nt = 0; nt < 4; ++nt)
                    acc[mt][nt] = __builtin_amdgcn_mfma_f32_16x16x32_f16(
                        af[mt], bf[nt], acc[mt][nt], 0, 0, 0);
        }
        __syncthreads();
    }

    // --- epilogue: D + beta*Xt -> Hout (D rows m=l via quad*4+r, cols n=v via lane15) ---
#pragma unroll
    for (int mt = 0; mt < 4; ++mt) {
#pragma unroll
        for (int nt = 0; nt < 4; ++nt) {
            const int l = m0 + wm + mt * 16 + quad * 4;
            const int v = n0 + wn + nt * 16 + lane15;
            const size_t base = coff + (size_t)l * NODES + v;
#pragma unroll
            for (int r = 0; r < 4; ++r) {
                const size_t a = base + (size_t)r * NODES;
                Hout[a] = (_Float16)(acc[mt][nt][r] + BETA_F * (float)Xt[a]);
            }
        }
    }
}

// ---------------------------------------------------------------------------
// out[b,o,v,l] = bias[o] + sum_c Wt[c][o]*X[c] (fp32) + dot2 pairs over H1..H3
// grid: (v=512, b=8), thread = l.
__global__ __launch_bounds__(256) void final_kernel(
    const float* __restrict__ X,
    const _Float16* __restrict__ H1,
    const _Float16* __restrict__ H2,
    const _Float16* __restrict__ H3,
    const float* __restrict__ Wt,
    const unsigned int* __restrict__ Wp,
    const float* __restrict__ bias,
    float* __restrict__ out)
{
    const int v = blockIdx.x, b = blockIdx.y, l = threadIdx.x;
    const size_t vl = (size_t)v * SEQL + l;

    float acc[COUT];
#pragma unroll
    for (int o = 0; o < COUT; ++o) acc[o] = bias[o];

    // group 0: original fp32 X, plain fmac
    {
        const float* P = X + (size_t)b * CIN * PLANE + vl;
        for (int c = 0; c < CIN; ++c) {
            const float x = P[(size_t)c * PLANE];
            const float* wr = Wt + c * COUT;
#pragma unroll
            for (int o = 0; o < COUT; ++o) acc[o] += wr[o] * x;
        }
    }
    // groups 1..3: f16 hop planes, v_dot2_f32_f16 over channel pairs
    const _Float16* Hs[3] = {H1, H2, H3};
#pragma unroll
    for (int g = 0; g < 3; ++g) {
        const _Float16* P = Hs[g] + (size_t)b * CIN * PLANE + vl;
        for (int cp = 0; cp < 16; ++cp) {
            const _Float16 h0 = P[(size_t)(2 * cp) * PLANE];
            const _Float16 h1 = P[(size_t)(2 * cp + 1) * PLANE];
            const f16x2 hp = {h0, h1};
            const unsigned int* wr = Wp + ((g + 1) * 16 + cp) * COUT;
#pragma unroll
            for (int o = 0; o < COUT; ++o)
                acc[o] = __builtin_amdgcn_fdot2(hp, __builtin_bit_cast(f16x2, wr[o]),
                                                acc[o], false);
        }
    }
    float* O = out + (size_t)b * COUT * PLANE + vl;
#pragma unroll
    for (int o = 0; o < COUT; ++o) O[(size_t)o * PLANE] = acc[o];
}

// ---------------------------------------------------------------------------
extern "C" void kernel_launch(void* const* d_in, const int* in_sizes, int n_in,
                              void* d_out, int out_size, void* d_ws, size_t ws_size,
                              hipStream_t stream) {
    (void)in_sizes; (void)n_in; (void)out_size; (void)ws_size;
    const float* X    = (const float*)d_in[0];
    const float* A    = (const float*)d_in[1];
    const float* W    = (const float*)d_in[2];
    const float* bias = (const float*)d_in[3];
    float* out = (float*)d_out;
    char* w = (char*)d_ws;

    // ws layout (1 GiB available; we use 449 MiB)
    const size_t MB = 1ull << 20;
    float*          Wt  = (float*)(w);                    // 32 KB
    unsigned int*   Wp  = (unsigned int*)(w + 64 * 1024); // 16 KB
    _Float16*       Apb = (_Float16*)(w + 128 * 1024);    // 512 KB
    _Float16*       Xt  = (_Float16*)(w + 1 * MB);        // 64 MB
    _Float16*       Ht1 = (_Float16*)(w + 65 * MB);
    _Float16*       Ht2 = (_Float16*)(w + 129 * MB);
    _Float16*       Ht3 = (_Float16*)(w + 193 * MB);
    _Float16*       Hn1 = (_Float16*)(w + 257 * MB);
    _Float16*       Hn2 = (_Float16*)(w + 321 * MB);
    _Float16*       Hn3 = (_Float16*)(w + 385 * MB);

    norm_A_kernel<<<dim3(NODES), dim3(256), 0, stream>>>(A, Apb);
    prep_W_kernel<<<dim3(32), dim3(256), 0, stream>>>(W, Wt, Wp);
    prep_X_kernel<<<dim3(4, 8, 256), dim3(256), 0, stream>>>(X, (unsigned short*)Xt);

    const dim3 pgrid(4, 2, 256);   // v-tiles, l-tiles, (b,c) chunks
    const dim3 tgrid(8, 4, 256);

    prop_mfma_kernel<<<pgrid, 256, 0, stream>>>(Apb, Xt, Xt, Ht1);
    transpose_h_kernel<<<tgrid, 256, 0, stream>>>((const unsigned short*)Ht1, (unsigned short*)Hn1);
    prop_mfma_kernel<<<pgrid, 256, 0, stream>>>(Apb, Ht1, Xt, Ht2);
    transpose_h_kernel<<<tgrid, 256, 0, stream>>>((const unsigned short*)Ht2, (unsigned short*)Hn2);
    prop_mfma_kernel<<<pgrid, 256, 0, stream>>>(Apb, Ht2, Xt, Ht3);
    transpose_h_kernel<<<tgrid, 256, 0, stream>>>((const unsigned short*)Ht3, (unsigned short*)Hn3);

    final_kernel<<<dim3(NODES, NB), dim3(256), 0, stream>>>(X, Hn1, Hn2, Hn3, Wt, Wp, bias, out);
}